// Round 3
// baseline (609.067 us; speedup 1.0000x reference)
//
#include <hip/hip_runtime.h>

// LPKT forward. B=64, S=128, NQ=2000, C=128, K=64, DE=DC=64.
// R3: h persistent in registers (G^T MFMA orientation), 3 barriers/step,
// tail-phase h_tilde on waves 4-7, algebraic precompute collapse (T/U tables).

constexpr int BB = 64;    // batch
constexpr int SS = 128;   // seq len
constexpr int CD = 128;   // C (concepts)
constexpr int KK = 64;    // K
constexpr int HP = 68;    // padded LDS row stride for h copy (dword-bank decorrelated)

typedef short bf16x8 __attribute__((ext_vector_type(8)));
typedef float f32x4  __attribute__((ext_vector_type(4)));

__device__ __forceinline__ short f2bf(float x) {           // fp32 -> bf16 RNE
  unsigned u = __builtin_bit_cast(unsigned, x);
  unsigned r = u + 0x7fffu + ((u >> 16) & 1u);
  return (short)(r >> 16);
}
__device__ __forceinline__ float sigm(float x) { return 1.f / (1.f + __expf(-x)); }
__device__ __forceinline__ bf16x8 pack8(float4 a, float4 b) {
  bf16x8 r;
  r[0] = f2bf(a.x); r[1] = f2bf(a.y); r[2] = f2bf(a.z); r[3] = f2bf(a.w);
  r[4] = f2bf(b.x); r[5] = f2bf(b.y); r[6] = f2bf(b.z); r[7] = f2bf(b.w);
  return r;
}

// ---------------------------------------------------------------------------
// pcK: grid=5, block=256.
// Blocks 0..3: K_m = W1[0:64]^T-projected slabs:  K_m[d][k] = sum_j W1[d][j]*src_m[j][k]
//   m=0: W2[0:64], m=1: W2[64:128], m=2: W3[0:64], m=3: W3[64:128]
// Block 4: U vectors: alc[cr] = Ec[cr]@W1[64:128] + b1; U_*[cr] = alc[cr]@slab.
__global__ void pcK(const float* __restrict__ W1, const float* __restrict__ W2,
                    const float* __restrict__ W3, const float* __restrict__ Ec,
                    const float* __restrict__ b1,
                    float* __restrict__ Kws, float* __restrict__ Uws) {
  int m = blockIdx.x, tid = threadIdx.x;
  if (m < 4) {
    const float* src = (m < 2 ? W2 : W3) + (m & 1) * 64 * 64;
    int k = tid & 63, dg = tid >> 6;   // dg 0..3
    float acc[16];
    #pragma unroll
    for (int i = 0; i < 16; ++i) acc[i] = 0.f;
    for (int j = 0; j < 64; ++j) {
      float w = src[j * 64 + k];
      #pragma unroll
      for (int i = 0; i < 16; ++i) acc[i] += W1[(dg * 16 + i) * 64 + j] * w;
    }
    #pragma unroll
    for (int i = 0; i < 16; ++i) Kws[m * 4096 + (dg * 16 + i) * 64 + k] = acc[i];
  } else {
    __shared__ float alc[2][64];
    if (tid < 128) {
      int cr = tid >> 6, k = tid & 63;
      float s = b1[k];
      for (int d = 0; d < 64; ++d) s += Ec[cr * 64 + d] * W1[(64 + d) * 64 + k];
      alc[cr][k] = s;
    }
    __syncthreads();
    if (tid < 128) {
      int cr = tid >> 6, k = tid & 63;
      float u2a = 0.f, u2b = 0.f, u3a = 0.f, u3b = 0.f;
      for (int j = 0; j < 64; ++j) {
        float a = alc[cr][j];
        u2a += a * W2[j * 64 + k];       u2b += a * W2[(64 + j) * 64 + k];
        u3a += a * W3[j * 64 + k];       u3b += a * W3[(64 + j) * 64 + k];
      }
      Uws[(0 + cr) * 64 + k] = u2a;  Uws[(2 + cr) * 64 + k] = u2b;
      Uws[(4 + cr) * 64 + k] = u3a;  Uws[(6 + cr) * 64 + k] = u3b;
    }
  }
}

// ---------------------------------------------------------------------------
// pcT: grid=2000 (one per question), block=128.
// T[q][m*64+k] = sum_d Eq[q][d] K_m[d][k]  (m=0..3)
// DIFF[q][c]   = qmat[q][c]*sigm(Eq[q]@Wdiff + bdiff)[c];  DISCq[q] = 5*sigm(Eq[q]@Wdisc+bdisc)
__global__ void pcT(const float* __restrict__ Eq, const float* __restrict__ qmat,
                    const float* __restrict__ Wdiff, const float* __restrict__ bdiff,
                    const float* __restrict__ Wdisc, const float* __restrict__ bdisc,
                    const float* __restrict__ Kws,
                    float* __restrict__ T, float* __restrict__ DIFF, float* __restrict__ DISCq) {
  int q = blockIdx.x, tid = threadIdx.x;
  __shared__ float e[64];
  if (tid < 64) e[tid] = Eq[q * 64 + tid];
  __syncthreads();
  int k = tid & 63, half = tid >> 6;
  for (int m = half; m < 4; m += 2) {
    float s = 0.f;
    #pragma unroll 16
    for (int d = 0; d < 64; ++d) s += e[d] * Kws[m * 4096 + d * 64 + k];
    T[q * 256 + m * 64 + k] = s;
  }
  float s = 0.f;
  #pragma unroll 16
  for (int d = 0; d < 64; ++d) s += e[d] * Wdiff[d * 128 + tid];
  DIFF[q * 128 + tid] = qmat[q * 128 + tid] * sigm(s + bdiff[tid]);
  if (tid == 0) {
    float s2 = 0.f;
    for (int d = 0; d < 64; ++d) s2 += e[d] * Wdisc[d];
    DISCq[q] = 5.f * sigm(s2 + bdisc[0]);
  }
}

// ---------------------------------------------------------------------------
// Main kernel. grid=64 (1 WG/batch), block=512 (8 waves). Wave w owns c-band
// [16w,16w+16). h persistent in registers in the G^T C/D layout:
//   lane(quad,col): c = 16*wv+col,  k = mb*16 + quad*4 + reg  (mb=0..3, reg=0..3)
// MFMA lane maps (HW-verified via R2): A/B frag: (lane&15, quad*8+j); C/D: (col, quad*4+reg).
__global__ __launch_bounds__(512, 1) void lpkt_main(
    const int* __restrict__ qs, const int* __restrict__ cs,
    const float* __restrict__ qmat, const float* __restrict__ h0,
    const float* __restrict__ W2, const float* __restrict__ b2,
    const float* __restrict__ W3, const float* __restrict__ b3,
    const float* __restrict__ W4, const float* __restrict__ b4,
    const float* __restrict__ Wab, const float* __restrict__ bab,
    const float* __restrict__ T, const float* __restrict__ Uws,
    const float* __restrict__ DIFF, const float* __restrict__ DISCq,
    float* __restrict__ out) {
  __shared__ __align__(16) float hs[CD * HP];      // fp32 h copy (frag + tail reads)
  __shared__ __align__(16) float qrow[2][CD];      // ping-pong q_matrix rows
  __shared__ __align__(16) float lg_s[KK], tvec_s[KK], ht_s[KK];
  __shared__ __align__(16) float ypart[CD];
  __shared__ __align__(16) float P4[4 * KK];       // h_tilde partials: [w][k]
  __shared__ __align__(16) float Us[8 * KK];       // U tables
  __shared__ __align__(16) short bwbt[8 * 64 * 8]; // W4b bf16 frags (wave0 tvec)

  const int b    = blockIdx.x;
  const int tid  = threadIdx.x;
  const int lane = tid & 63;
  const int wv   = tid >> 6;       // 0..7
  const int col  = lane & 15;
  const int quad = lane >> 4;      // 0..3
  const int bS   = b * SS;
  const int c_my = 16 * wv + col;

  const float* W4a = W4;
  const float* W4b = W4 + 64 * 64;
  const float* W2c = W2 + 128 * 64;
  const float* W3c = W3 + 128 * 64;
  const float bab0 = bab[0];
  const f32x4 zz = {0.f, 0.f, 0.f, 0.f};

  // ---- init ----
  float4 h2v[4], wabr[4];
  #pragma unroll
  for (int mb = 0; mb < 4; ++mb) {
    h2v[mb]  = *(const float4*)&h0[c_my * 64 + mb * 16 + quad * 4];
    wabr[mb] = *(const float4*)&Wab[mb * 16 + quad * 4];
    *(float4*)&hs[c_my * HP + mb * 16 + quad * 4] = h2v[mb];
  }
  Us[tid] = Uws[tid];
  if (tid < 128) qrow[0][tid] = qmat[qs[bS] * CD + tid];
  if (tid == 0)  out[bS] = 0.f;

  // W4a^T A-fragments (all waves; same data layout as a B-fragment of W4a)
  bf16x8 bw4[4][2];
  #pragma unroll
  for (int mb = 0; mb < 4; ++mb)
    #pragma unroll
    for (int kh = 0; kh < 2; ++kh)
      #pragma unroll
      for (int j = 0; j < 8; ++j)
        bw4[mb][kh][j] = f2bf(W4a[(kh * 32 + quad * 8 + j) * 64 + mb * 16 + col]);

  // wave0 persistent state
  bf16x8 bw2[4][2], bw3[4][2];
  float b2r[4], b3r[4], b4r[4];
  float tB2[4], tB3[4], tA2[4], tA3[4];
  int qA = 0, cA = 0, cB = 0;
  if (wv == 0) {
    qA = qs[bS]; cA = cs[bS];
    #pragma unroll
    for (int nb = 0; nb < 4; ++nb) {
      #pragma unroll
      for (int kh = 0; kh < 2; ++kh) {
        bf16x8 fb;
        #pragma unroll
        for (int j = 0; j < 8; ++j) {
          int kk = (kh * 32 + quad * 8 + j) * 64 + nb * 16 + col;
          bw2[nb][kh][j] = f2bf(W2c[kk]);
          bw3[nb][kh][j] = f2bf(W3c[kk]);
          fb[j] = f2bf(W4b[kk]);
        }
        *(bf16x8*)&bwbt[((nb * 2 + kh) * 64 + lane) * 8] = fb;
      }
      int k = nb * 16 + col;
      b2r[nb] = b2[k]; b3r[nb] = b3[k]; b4r[nb] = b4[k];
      tB2[nb] = T[qA * 256 + 64 + k];
      tB3[nb] = T[qA * 256 + 192 + k];
      tA2[nb] = 0.f; tA3[nb] = 0.f;
    }
  }
  __syncthreads();                                 // B0

  // tail0: h_tilde partials for t=1 (qrow[0] . h0)
  if (wv >= 4) {
    int cpart = (wv - 4) * 4 + quad;
    float4 a = {0.f, 0.f, 0.f, 0.f};
    #pragma unroll
    for (int i = 0; i < 8; ++i) {
      int c = cpart * 8 + i;
      float qc = qrow[0][c];
      float4 hv = *(const float4*)&hs[c * HP + col * 4];
      a.x += qc * hv.x; a.y += qc * hv.y; a.z += qc * hv.z; a.w += qc * hv.w;
    }
    a.x += __shfl_xor(a.x, 16); a.x += __shfl_xor(a.x, 32);
    a.y += __shfl_xor(a.y, 16); a.y += __shfl_xor(a.y, 32);
    a.z += __shfl_xor(a.z, 16); a.z += __shfl_xor(a.z, 32);
    a.w += __shfl_xor(a.w, 16); a.w += __shfl_xor(a.w, 32);
    if (lane < 16) *(float4*)&P4[(wv - 4) * 64 + lane * 4] = a;
  }

  float dq0 = 0.f, dq1 = 0.f, dsc = 0.f;

  for (int t = 1; t < SS; ++t) {
    __syncthreads();                               // B3: P4 (and init) published

    // ================= HEAD =================
    // all waves: h fragment loads from LDS copy (issued early)
    float4 hf0a = *(const float4*)&hs[c_my * HP + quad * 8];
    float4 hf0b = *(const float4*)&hs[c_my * HP + quad * 8 + 4];
    float4 hf1a = *(const float4*)&hs[c_my * HP + 32 + quad * 8];
    float4 hf1b = *(const float4*)&hs[c_my * HP + 32 + quad * 8 + 4];

    if (wv == 0) {
      // prefetch next step's T rows + indices
      int q_t = 0, c_t = 0;
      float tB2n[4], tB3n[4], tA2n[4], tA3n[4];
      if (t < SS - 1) {
        q_t = qs[bS + t]; c_t = cs[bS + t];
        #pragma unroll
        for (int nb = 0; nb < 4; ++nb) {
          int k = nb * 16 + col;
          tA2n[nb] = T[qA * 256 + k];
          tA3n[nb] = T[qA * 256 + 128 + k];
          tB2n[nb] = T[q_t * 256 + 64 + k];
          tB3n[nb] = T[q_t * 256 + 192 + k];
        }
      }
      // bases
      float base2[4], base3[4];
      #pragma unroll
      for (int nb = 0; nb < 4; ++nb) {
        int k = nb * 16 + col;
        base2[nb] = b2r[nb] + tB2[nb] + Us[(2 + cA) * 64 + k];
        base3[nb] = b3r[nb] + tB3[nb] + Us[(6 + cA) * 64 + k];
        if (t >= 2) {
          base2[nb] += tA2[nb] + Us[(0 + cB) * 64 + k];
          base3[nb] += tA3[nb] + Us[(4 + cB) * 64 + k];
        }
      }
      // h_tilde from partials
      float htk = P4[lane] + P4[64 + lane] + P4[128 + lane] + P4[192 + lane];
      ht_s[lane] = htk;
      float4 x0 = *(const float4*)&ht_s[quad * 8];
      float4 x1 = *(const float4*)&ht_s[quad * 8 + 4];
      float4 x2 = *(const float4*)&ht_s[32 + quad * 8];
      float4 x3 = *(const float4*)&ht_s[32 + quad * 8 + 4];
      bf16x8 hf0 = pack8(x0, x1), hf1 = pack8(x2, x3);
      f32x4 a2v[4], a3v[4];
      #pragma unroll
      for (int nb = 0; nb < 4; ++nb) {
        a2v[nb] = __builtin_amdgcn_mfma_f32_16x16x32_bf16(hf0, bw2[nb][0], zz, 0, 0, 0);
        a2v[nb] = __builtin_amdgcn_mfma_f32_16x16x32_bf16(hf1, bw2[nb][1], a2v[nb], 0, 0, 0);
        a3v[nb] = __builtin_amdgcn_mfma_f32_16x16x32_bf16(hf0, bw3[nb][0], zz, 0, 0, 0);
        a3v[nb] = __builtin_amdgcn_mfma_f32_16x16x32_bf16(hf1, bw3[nb][1], a3v[nb], 0, 0, 0);
      }
      #pragma unroll
      for (int nb = 0; nb < 4; ++nb) {
        float u2 = a2v[nb][0] + base2[nb];
        float u3 = a3v[nb][0] + base3[nb];
        float lgn = sigm(u3) * sigm(2.f * u2);     // sigm(g3)*(tanh(g2)+1)/2
        if (quad == 0) lg_s[nb * 16 + col] = lgn;
      }
      // tvec = LG @ W4b + b4
      float4 l0 = *(const float4*)&lg_s[quad * 8];
      float4 l1 = *(const float4*)&lg_s[quad * 8 + 4];
      float4 l2 = *(const float4*)&lg_s[32 + quad * 8];
      float4 l3 = *(const float4*)&lg_s[32 + quad * 8 + 4];
      bf16x8 lf0 = pack8(l0, l1), lf1 = pack8(l2, l3);
      #pragma unroll
      for (int nb = 0; nb < 4; ++nb) {
        bf16x8 wb0 = *(const bf16x8*)&bwbt[((nb * 2 + 0) * 64 + lane) * 8];
        bf16x8 wb1 = *(const bf16x8*)&bwbt[((nb * 2 + 1) * 64 + lane) * 8];
        f32x4 bb = __builtin_amdgcn_mfma_f32_16x16x32_bf16(lf0, wb0, zz, 0, 0, 0);
        bb = __builtin_amdgcn_mfma_f32_16x16x32_bf16(lf1, wb1, bb, 0, 0, 0);
        if (quad == 0) tvec_s[nb * 16 + col] = bb[0] + b4r[nb];
      }
      // shift prefetch state
      if (t < SS - 1) {
        #pragma unroll
        for (int nb = 0; nb < 4; ++nb) {
          tA2[nb] = tA2n[nb]; tA3[nb] = tA3n[nb];
          tB2[nb] = tB2n[nb]; tB3[nb] = tB3n[nb];
        }
        cB = cA; cA = c_t; qA = q_t;
      }
    } else if (wv == 1) {                          // prefetch DIFF/DISC for tail
      int qt = qs[bS + t];
      dq0 = DIFF[qt * CD + lane];
      dq1 = DIFF[qt * CD + 64 + lane];
      dsc = DISCq[qt];
    } else if (wv == 2) {                          // q_next row
      int row = qs[bS + t];
      qrow[t & 1][lane]      = qmat[row * CD + lane];
      qrow[t & 1][64 + lane] = qmat[row * CD + 64 + lane];
    }

    // all waves: G^T = W4a^T . h^T  (per-wave 16-c band)
    bf16x8 af0 = pack8(hf0a, hf0b), af1 = pack8(hf1a, hf1b);
    f32x4 acc[4];
    #pragma unroll
    for (int mb = 0; mb < 4; ++mb) {
      acc[mb] = __builtin_amdgcn_mfma_f32_16x16x32_bf16(bw4[mb][0], af0, zz, 0, 0, 0);
      acc[mb] = __builtin_amdgcn_mfma_f32_16x16x32_bf16(bw4[mb][1], af1, acc[mb], 0, 0, 0);
    }
    __syncthreads();                               // B1: lg/tvec/qrow published

    // ================= UPDATE =================
    float qe  = qrow[(t - 1) & 1][c_my];
    float qnv = qrow[t & 1][c_my];
    float sab = 0.f;
    #pragma unroll
    for (int mb = 0; mb < 4; ++mb) {
      float4 lgq = *(const float4*)&lg_s[mb * 16 + quad * 4];
      float4 tvq = *(const float4*)&tvec_s[mb * 16 + quad * 4];
      float4 h2 = h2v[mb];
      h2.x = qe * lgq.x + sigm(acc[mb][0] + tvq.x) * h2.x;
      h2.y = qe * lgq.y + sigm(acc[mb][1] + tvq.y) * h2.y;
      h2.z = qe * lgq.z + sigm(acc[mb][2] + tvq.z) * h2.z;
      h2.w = qe * lgq.w + sigm(acc[mb][3] + tvq.w) * h2.w;
      h2v[mb] = h2;
      sab += h2.x * wabr[mb].x + h2.y * wabr[mb].y + h2.z * wabr[mb].z + h2.w * wabr[mb].w;
      *(float4*)&hs[c_my * HP + mb * 16 + quad * 4] = h2;
    }
    sab += __shfl_xor(sab, 16);
    sab += __shfl_xor(sab, 32);
    if (lane < 16) ypart[16 * wv + lane] = sab;
    (void)qnv;
    __syncthreads();                               // B2: hs/ypart published

    // ================= TAIL =================
    if (wv >= 4) {
      if (t < SS - 1) {                            // h_tilde partials for t+1
        const float* qn = qrow[t & 1];
        int cpart = (wv - 4) * 4 + quad;
        float4 a = {0.f, 0.f, 0.f, 0.f};
        #pragma unroll
        for (int i = 0; i < 8; ++i) {
          int c = cpart * 8 + i;
          float qc = qn[c];
          float4 hv = *(const float4*)&hs[c * HP + col * 4];
          a.x += qc * hv.x; a.y += qc * hv.y; a.z += qc * hv.z; a.w += qc * hv.w;
        }
        a.x += __shfl_xor(a.x, 16); a.x += __shfl_xor(a.x, 32);
        a.y += __shfl_xor(a.y, 16); a.y += __shfl_xor(a.y, 32);
        a.z += __shfl_xor(a.z, 16); a.z += __shfl_xor(a.z, 32);
        a.w += __shfl_xor(a.w, 16); a.w += __shfl_xor(a.w, 32);
        if (lane < 16) *(float4*)&P4[(wv - 4) * 64 + lane * 4] = a;
      }
    } else if (wv == 1) {                          // finish y
      const float* qn = qrow[t & 1];
      float v = (sigm(ypart[lane] + bab0) * qn[lane] - dq0)
              + (sigm(ypart[64 + lane] + bab0) * qn[64 + lane] - dq1);
      v += __shfl_xor(v, 32); v += __shfl_xor(v, 16); v += __shfl_xor(v, 8);
      v += __shfl_xor(v, 4);  v += __shfl_xor(v, 2);  v += __shfl_xor(v, 1);
      if (lane == 0) out[bS + t] = sigm(dsc * v);
    }
  }
}

// ---------------------------------------------------------------------------
extern "C" void kernel_launch(void* const* d_in, const int* in_sizes, int n_in,
                              void* d_out, int out_size, void* d_ws, size_t ws_size,
                              hipStream_t stream) {
  const int*   qs    = (const int*)d_in[0];
  const int*   cs    = (const int*)d_in[1];
  const float* qmat  = (const float*)d_in[2];
  const float* Eq    = (const float*)d_in[3];
  const float* Ec    = (const float*)d_in[4];
  const float* h0    = (const float*)d_in[5];
  const float* W1    = (const float*)d_in[6];
  const float* b1    = (const float*)d_in[7];
  const float* W2    = (const float*)d_in[8];
  const float* b2    = (const float*)d_in[9];
  const float* W3    = (const float*)d_in[10];
  const float* b3    = (const float*)d_in[11];
  const float* W4    = (const float*)d_in[12];
  const float* b4    = (const float*)d_in[13];
  const float* Wab   = (const float*)d_in[14];
  const float* bab   = (const float*)d_in[15];
  const float* Wdiff = (const float*)d_in[16];
  const float* bdiff = (const float*)d_in[17];
  const float* Wdisc = (const float*)d_in[18];
  const float* bdisc = (const float*)d_in[19];
  float* out = (float*)d_out;

  float* w = (float*)d_ws;
  float* Kws   = w;                       // 4*64*64          = 16384
  float* Uws   = Kws + 16384;             // 8*64             = 512
  float* T     = Uws + 512;               // 2000*256         = 512000
  float* DIFF  = T + 512000;              // 2000*128         = 256000
  float* DISCq = DIFF + 256000;           // 2000

  pcK<<<5, 256, 0, stream>>>(W1, W2, W3, Ec, b1, Kws, Uws);
  pcT<<<2000, 128, 0, stream>>>(Eq, qmat, Wdiff, bdiff, Wdisc, bdisc, Kws, T, DIFF, DISCq);
  lpkt_main<<<BB, 512, 0, stream>>>(qs, cs, qmat, h0, W2, b2, W3, b3, W4, b4, Wab, bab,
                                    T, Uws, DIFF, DISCq, out);
}

// Round 4
// 564.985 us; speedup vs baseline: 1.0780x; 1.0780x over previous
//
#include <hip/hip_runtime.h>

// LPKT forward. B=64, S=128, NQ=2000, C=128, K=64, DE=DC=64.
// R4: 2 barriers/step; per-(b,t) precomputed record stream (no scattered loads
// in main loop); bf16 h in LDS (k-contig, direct MFMA A-frag b128 reads) +
// fp32 h in registers; h_tilde via ds_add ping-pong; ability via MFMA.

constexpr int BB = 64, SS = 128, CD = 128, KK = 64;
constexpr int RECF = 264;     // floats per record: BASE2[64]|BASE3[64]|DIFF[128]|QBITS[4]|DISC|pad
constexpr int HPB  = 72;      // shorts per h row in LDS

typedef short bf16x8 __attribute__((ext_vector_type(8)));
typedef float f32x4  __attribute__((ext_vector_type(4)));

__device__ __forceinline__ short f2bf(float x) {
  unsigned u = __builtin_bit_cast(unsigned, x);
  unsigned r = u + 0x7fffu + ((u >> 16) & 1u);
  return (short)(r >> 16);
}
__device__ __forceinline__ float sigm(float x) { return 1.f / (1.f + __expf(-x)); }
__device__ __forceinline__ bf16x8 pack8(float4 a, float4 b) {
  bf16x8 r;
  r[0] = f2bf(a.x); r[1] = f2bf(a.y); r[2] = f2bf(a.z); r[3] = f2bf(a.w);
  r[4] = f2bf(b.x); r[5] = f2bf(b.y); r[6] = f2bf(b.z); r[7] = f2bf(b.w);
  return r;
}

// ---------------------------------------------------------------------------
// pcK: K-slab projections of W1 through W2/W3 + correctness-table U vectors.
__global__ void pcK(const float* __restrict__ W1, const float* __restrict__ W2,
                    const float* __restrict__ W3, const float* __restrict__ Ec,
                    const float* __restrict__ b1,
                    float* __restrict__ Kws, float* __restrict__ Uws) {
  int m = blockIdx.x, tid = threadIdx.x;
  if (m < 4) {
    const float* src = (m < 2 ? W2 : W3) + (m & 1) * 64 * 64;
    int k = tid & 63, dg = tid >> 6;
    float acc[16];
    #pragma unroll
    for (int i = 0; i < 16; ++i) acc[i] = 0.f;
    for (int j = 0; j < 64; ++j) {
      float w = src[j * 64 + k];
      #pragma unroll
      for (int i = 0; i < 16; ++i) acc[i] += W1[(dg * 16 + i) * 64 + j] * w;
    }
    #pragma unroll
    for (int i = 0; i < 16; ++i) Kws[m * 4096 + (dg * 16 + i) * 64 + k] = acc[i];
  } else {
    __shared__ float alc[2][64];
    if (tid < 128) {
      int cr = tid >> 6, k = tid & 63;
      float s = b1[k];
      for (int d = 0; d < 64; ++d) s += Ec[cr * 64 + d] * W1[(64 + d) * 64 + k];
      alc[cr][k] = s;
    }
    __syncthreads();
    if (tid < 128) {
      int cr = tid >> 6, k = tid & 63;
      float u2a = 0.f, u2b = 0.f, u3a = 0.f, u3b = 0.f;
      for (int j = 0; j < 64; ++j) {
        float a = alc[cr][j];
        u2a += a * W2[j * 64 + k];       u2b += a * W2[(64 + j) * 64 + k];
        u3a += a * W3[j * 64 + k];       u3b += a * W3[(64 + j) * 64 + k];
      }
      Uws[(0 + cr) * 64 + k] = u2a;  Uws[(2 + cr) * 64 + k] = u2b;
      Uws[(4 + cr) * 64 + k] = u3a;  Uws[(6 + cr) * 64 + k] = u3b;
    }
  }
}

// ---------------------------------------------------------------------------
// pcT: per-question tables T (4 slab projections), DIFF (q-masked), DISCq.
__global__ void pcT(const float* __restrict__ Eq, const float* __restrict__ qmat,
                    const float* __restrict__ Wdiff, const float* __restrict__ bdiff,
                    const float* __restrict__ Wdisc, const float* __restrict__ bdisc,
                    const float* __restrict__ Kws,
                    float* __restrict__ T, float* __restrict__ DIFF, float* __restrict__ DISCq) {
  int q = blockIdx.x, tid = threadIdx.x;
  __shared__ float e[64];
  if (tid < 64) e[tid] = Eq[q * 64 + tid];
  __syncthreads();
  int k = tid & 63, half = tid >> 6;
  for (int m = half; m < 4; m += 2) {
    float s = 0.f;
    #pragma unroll 16
    for (int d = 0; d < 64; ++d) s += e[d] * Kws[m * 4096 + d * 64 + k];
    T[q * 256 + m * 64 + k] = s;
  }
  float s = 0.f;
  #pragma unroll 16
  for (int d = 0; d < 64; ++d) s += e[d] * Wdiff[d * 128 + tid];
  DIFF[q * 128 + tid] = qmat[q * 128 + tid] * sigm(s + bdiff[tid]);
  if (tid == 0) {
    float s2 = 0.f;
    for (int d = 0; d < 64; ++d) s2 += e[d] * Wdisc[d];
    DISCq[q] = 5.f * sigm(s2 + bdisc[0]);
  }
}

// ---------------------------------------------------------------------------
// pcR: per-(b,t) record gather. grid = B*S, block = 128.
__global__ void pcR(const int* __restrict__ qs, const int* __restrict__ cs,
                    const float* __restrict__ qmat,
                    const float* __restrict__ b2, const float* __restrict__ b3,
                    const float* __restrict__ T, const float* __restrict__ Uws,
                    const float* __restrict__ DIFF, const float* __restrict__ DISCq,
                    float* __restrict__ REC) {
  int bs = blockIdx.x;
  int t  = bs & (SS - 1);
  int tid = threadIdx.x;
  int q_t = qs[bs];
  float* rec = REC + (size_t)bs * RECF;
  if (tid < 64) {
    int k = tid;
    float v2 = b2[k], v3 = b3[k];
    if (t >= 1) {
      int q1 = qs[bs - 1], c1 = cs[bs - 1];
      v2 += T[q1 * 256 + 64 + k]  + Uws[(2 + c1) * 64 + k];
      v3 += T[q1 * 256 + 192 + k] + Uws[(6 + c1) * 64 + k];
    }
    if (t >= 2) {
      int q2 = qs[bs - 2], c2 = cs[bs - 2];
      v2 += T[q2 * 256 + k]       + Uws[(0 + c2) * 64 + k];
      v3 += T[q2 * 256 + 128 + k] + Uws[(4 + c2) * 64 + k];
    }
    rec[k] = v2; rec[64 + k] = v3;
  }
  rec[128 + tid] = DIFF[q_t * 128 + tid];
  unsigned long long m = __ballot(qmat[q_t * 128 + tid] > 0.5f);
  int wv = tid >> 6, lane = tid & 63;
  if (lane == 0) {
    rec[256 + wv * 2]     = __uint_as_float((unsigned)m);
    rec[256 + wv * 2 + 1] = __uint_as_float((unsigned)(m >> 32));
  }
  if (tid == 0) rec[260] = DISCq[q_t];
}

// ---------------------------------------------------------------------------
// Main. grid=64, block=512 (8 waves). Wave w owns c-band [16w,16w+16).
// h fp32 in registers h2[reg][n] at (c=16wv+4quad+reg, k=n*16+col); bf16 copy
// in LDS hsb (k-contig) for MFMA A-frags. 2 barriers/step.
__global__ __launch_bounds__(512, 1) void lpkt_main(
    const float* __restrict__ h0,
    const float* __restrict__ W2, const float* __restrict__ W3,
    const float* __restrict__ W4, const float* __restrict__ b4,
    const float* __restrict__ Wab, const float* __restrict__ bab,
    const float* __restrict__ REC, float* __restrict__ out) {
  __shared__ __align__(16) short hsb[CD * HPB];        // 18432 B bf16 h
  __shared__ __align__(16) short w23f[2 * 4 * 2 * 64 * 8];  // 8192 B W2c/W3c frags
  __shared__ __align__(16) float recs[4][RECF];        // 4224 B record slots
  __shared__ __align__(16) float htbuf[2][KK];         // h_tilde ping-pong (ds_add)
  __shared__ __align__(16) float ypbuf[CD];            // raw ability dots
  __shared__ __align__(16) float lg_s[KK];
  __shared__ __align__(16) short lg_sb[KK];

  const int b    = blockIdx.x;
  const int tid  = threadIdx.x;
  const int lane = tid & 63;
  const int wv   = tid >> 6;
  const int col  = lane & 15;
  const int quad = lane >> 4;
  const int bS   = b * SS;
  const float bab0 = bab[0];
  const f32x4 zz = {0.f, 0.f, 0.f, 0.f};

  const float* W4a = W4;
  const float* W4b = W4 + 64 * 64;
  const float* W2c = W2 + 128 * 64;
  const float* W3c = W3 + 128 * 64;

  // ---- persistent register fragments ----
  bf16x8 bw4[4][2], bwb[4][2], bwab[2];
  float b4r[4];
  #pragma unroll
  for (int nb = 0; nb < 4; ++nb) {
    #pragma unroll
    for (int kh = 0; kh < 2; ++kh)
      #pragma unroll
      for (int j = 0; j < 8; ++j) {
        int kk = (kh * 32 + quad * 8 + j) * 64 + nb * 16 + col;
        bw4[nb][kh][j] = f2bf(W4a[kk]);
        bwb[nb][kh][j] = f2bf(W4b[kk]);
      }
    b4r[nb] = b4[nb * 16 + col];
  }
  #pragma unroll
  for (int kh = 0; kh < 2; ++kh)
    #pragma unroll
    for (int j = 0; j < 8; ++j)
      bwab[kh][j] = (col == 0) ? f2bf(Wab[kh * 32 + quad * 8 + j]) : (short)0;

  // ---- W2c/W3c fragments into LDS (wave0 consumes each step) ----
  for (int e = tid; e < 1024; e += 512) {
    int lane_ = e & 63, kh = (e >> 6) & 1, nb = (e >> 7) & 3, m = e >> 9;
    int q_ = lane_ >> 4, c_ = lane_ & 15;
    const float* src = m ? W3c : W2c;
    bf16x8 f;
    #pragma unroll
    for (int j = 0; j < 8; ++j)
      f[j] = f2bf(src[(kh * 32 + q_ * 8 + j) * 64 + nb * 16 + c_]);
    *(bf16x8*)&w23f[e * 8] = f;
  }

  // ---- h init (fp32 regs + bf16 LDS) ----
  float h2[4][4];
  #pragma unroll
  for (int reg = 0; reg < 4; ++reg)
    #pragma unroll
    for (int n = 0; n < 4; ++n) {
      int c = 16 * wv + 4 * quad + reg;
      h2[reg][n] = h0[c * 64 + n * 16 + col];
      hsb[c * HPB + n * 16 + col] = f2bf(h2[reg][n]);
    }

  // ---- records 0..2 + zero htbuf ----
  for (int s = 0; s < 3; ++s)
    if (tid < RECF) recs[s][tid] = REC[((size_t)bS + s) * RECF + tid];
  if (tid < 128) htbuf[tid >> 6][tid & 63] = 0.f;
  if (tid == 0) out[bS] = 0.f;
  __syncthreads();

  // qe0 from record 0 qbits; initial h_tilde -> htbuf[1]
  const int c0 = 16 * wv + 4 * quad;
  float qeR[4];
  {
    unsigned bits = __float_as_uint(recs[0][256 + (c0 >> 5)]);
    #pragma unroll
    for (int reg = 0; reg < 4; ++reg) qeR[reg] = (float)((bits >> ((c0 & 31) + reg)) & 1u);
    float pk[4];
    #pragma unroll
    for (int n = 0; n < 4; ++n) {
      pk[n] = qeR[0] * h2[0][n] + qeR[1] * h2[1][n] + qeR[2] * h2[2][n] + qeR[3] * h2[3][n];
      pk[n] += __shfl_xor(pk[n], 16);
      pk[n] += __shfl_xor(pk[n], 32);
    }
    if (quad == 0) {
      #pragma unroll
      for (int n = 0; n < 4; ++n) atomicAdd(&htbuf[1][n * 16 + col], pk[n]);
    }
  }
  __syncthreads();

  float4 vrec = {0.f, 0.f, 0.f, 0.f};
  float qnR[4] = {0.f, 0.f, 0.f, 0.f};

  for (int t = 1; t < SS; ++t) {
    const int rs = t & 3;
    // ================= P =================
    // A-frags of h(t-1) (bf16, direct b128 reads)
    bf16x8 af0 = *(const bf16x8*)&hsb[(16 * wv + col) * HPB + quad * 8];
    bf16x8 af1 = *(const bf16x8*)&hsb[(16 * wv + col) * HPB + 32 + quad * 8];
    // qn(t) bits
    {
      unsigned bits = __float_as_uint(recs[rs][256 + (c0 >> 5)]);
      #pragma unroll
      for (int reg = 0; reg < 4; ++reg) qnR[reg] = (float)((bits >> ((c0 & 31) + reg)) & 1u);
    }
    // G = h(t-1) @ W4a   +   ability dot of h(t-1)
    f32x4 acc[4];
    #pragma unroll
    for (int nb = 0; nb < 4; ++nb) {
      acc[nb] = __builtin_amdgcn_mfma_f32_16x16x32_bf16(af0, bw4[nb][0], zz, 0, 0, 0);
      acc[nb] = __builtin_amdgcn_mfma_f32_16x16x32_bf16(af1, bw4[nb][1], acc[nb], 0, 0, 0);
    }
    f32x4 ya = __builtin_amdgcn_mfma_f32_16x16x32_bf16(af0, bwab[0], zz, 0, 0, 0);
    ya = __builtin_amdgcn_mfma_f32_16x16x32_bf16(af1, bwab[1], ya, 0, 0, 0);
    if (col == 0) {
      #pragma unroll
      for (int reg = 0; reg < 4; ++reg) ypbuf[16 * wv + quad * 4 + reg] = ya[reg];
    }
    // stream: issue global load of record t+2 (committed to LDS in Q)
    if (t <= SS - 3) {
      if (wv == 2)      vrec = *(const float4*)&REC[((size_t)bS + t + 2) * RECF + lane * 4];
      else if (wv == 3 && lane * 4 + 256 < RECF + 252 && (64 + lane) * 4 < RECF + 3) {
        if ((64 + lane) * 4 < RECF) vrec = *(const float4*)&REC[((size_t)bS + t + 2) * RECF + (64 + lane) * 4];
      }
    }
    // zero next-parity h_tilde accumulator
    if (wv == 3 && lane < 64) htbuf[(t + 1) & 1][lane] = 0.f;
    // wave0: u2/u3 -> LG
    if (wv == 0) {
      float4 x0 = *(const float4*)&htbuf[t & 1][quad * 8];
      float4 x1 = *(const float4*)&htbuf[t & 1][quad * 8 + 4];
      float4 x2 = *(const float4*)&htbuf[t & 1][32 + quad * 8];
      float4 x3 = *(const float4*)&htbuf[t & 1][32 + quad * 8 + 4];
      bf16x8 hf0 = pack8(x0, x1), hf1 = pack8(x2, x3);
      #pragma unroll
      for (int nb = 0; nb < 4; ++nb) {
        bf16x8 w20 = *(const bf16x8*)&w23f[(((0 * 4 + nb) * 2 + 0) * 64 + lane) * 8];
        bf16x8 w21 = *(const bf16x8*)&w23f[(((0 * 4 + nb) * 2 + 1) * 64 + lane) * 8];
        bf16x8 w30 = *(const bf16x8*)&w23f[(((1 * 4 + nb) * 2 + 0) * 64 + lane) * 8];
        bf16x8 w31 = *(const bf16x8*)&w23f[(((1 * 4 + nb) * 2 + 1) * 64 + lane) * 8];
        f32x4 a2 = __builtin_amdgcn_mfma_f32_16x16x32_bf16(hf0, w20, zz, 0, 0, 0);
        a2 = __builtin_amdgcn_mfma_f32_16x16x32_bf16(hf1, w21, a2, 0, 0, 0);
        f32x4 a3 = __builtin_amdgcn_mfma_f32_16x16x32_bf16(hf0, w30, zz, 0, 0, 0);
        a3 = __builtin_amdgcn_mfma_f32_16x16x32_bf16(hf1, w31, a3, 0, 0, 0);
        float u2 = a2[0] + recs[rs][nb * 16 + col];
        float u3 = a3[0] + recs[rs][64 + nb * 16 + col];
        float lgn = sigm(u3) * sigm(2.f * u2);
        if (quad == 0) { lg_s[nb * 16 + col] = lgn; lg_sb[nb * 16 + col] = f2bf(lgn); }
      }
    }
    __syncthreads();                               // B1

    // ================= Q =================
    // tvec = LG @ W4b + b4 (per-wave redundant MFMA)
    bf16x8 lf0 = *(const bf16x8*)&lg_sb[quad * 8];
    bf16x8 lf1 = *(const bf16x8*)&lg_sb[32 + quad * 8];
    float tvv[4], lgv[4];
    #pragma unroll
    for (int nb = 0; nb < 4; ++nb) {
      f32x4 bb = __builtin_amdgcn_mfma_f32_16x16x32_bf16(lf0, bwb[nb][0], zz, 0, 0, 0);
      bb = __builtin_amdgcn_mfma_f32_16x16x32_bf16(lf1, bwb[nb][1], bb, 0, 0, 0);
      tvv[nb] = bb[0] + b4r[nb];
      lgv[nb] = lg_s[nb * 16 + col];
    }
    // gates + h update (registers) + bf16 LDS writeback
    #pragma unroll
    for (int reg = 0; reg < 4; ++reg) {
      int c = 16 * wv + 4 * quad + reg;
      #pragma unroll
      for (int n = 0; n < 4; ++n) {
        float g = sigm(acc[n][reg] + tvv[n]);
        h2[reg][n] = qeR[reg] * lgv[n] + g * h2[reg][n];
        hsb[c * HPB + n * 16 + col] = f2bf(h2[reg][n]);
      }
    }
    // h_tilde(t) partials -> htbuf[(t+1)&1]
    {
      float pk[4];
      #pragma unroll
      for (int n = 0; n < 4; ++n) {
        pk[n] = qnR[0] * h2[0][n] + qnR[1] * h2[1][n] + qnR[2] * h2[2][n] + qnR[3] * h2[3][n];
        pk[n] += __shfl_xor(pk[n], 16);
        pk[n] += __shfl_xor(pk[n], 32);
      }
      if (quad == 0) {
        #pragma unroll
        for (int n = 0; n < 4; ++n) atomicAdd(&htbuf[(t + 1) & 1][n * 16 + col], pk[n]);
      }
    }
    // commit prefetched record t+2
    if (t <= SS - 3) {
      if (wv == 2) *(float4*)&recs[(t + 2) & 3][lane * 4] = vrec;
      else if (wv == 3 && (64 + lane) * 4 < RECF) *(float4*)&recs[(t + 2) & 3][(64 + lane) * 4] = vrec;
    }
    // y(t-1) finish on wave1
    if (wv == 1 && t >= 2) {
      const int rp = (t - 1) & 3;
      unsigned bl = __float_as_uint(recs[rp][256 + (lane >> 5)]);
      unsigned bh = __float_as_uint(recs[rp][258 + (lane >> 5)]);
      float q0 = (float)((bl >> (lane & 31)) & 1u);
      float q1 = (float)((bh >> (lane & 31)) & 1u);
      float v = sigm(ypbuf[lane] + bab0) * q0 - recs[rp][128 + lane]
              + sigm(ypbuf[64 + lane] + bab0) * q1 - recs[rp][128 + 64 + lane];
      v += __shfl_xor(v, 32); v += __shfl_xor(v, 16); v += __shfl_xor(v, 8);
      v += __shfl_xor(v, 4);  v += __shfl_xor(v, 2);  v += __shfl_xor(v, 1);
      if (lane == 0) out[bS + t - 1] = sigm(recs[rp][260] * v);
    }
    #pragma unroll
    for (int reg = 0; reg < 4; ++reg) qeR[reg] = qnR[reg];
    __syncthreads();                               // B2
  }

  // ---- epilogue: y(127) ----
  {
    bf16x8 af0 = *(const bf16x8*)&hsb[(16 * wv + col) * HPB + quad * 8];
    bf16x8 af1 = *(const bf16x8*)&hsb[(16 * wv + col) * HPB + 32 + quad * 8];
    f32x4 ya = __builtin_amdgcn_mfma_f32_16x16x32_bf16(af0, bwab[0], zz, 0, 0, 0);
    ya = __builtin_amdgcn_mfma_f32_16x16x32_bf16(af1, bwab[1], ya, 0, 0, 0);
    if (col == 0) {
      #pragma unroll
      for (int reg = 0; reg < 4; ++reg) ypbuf[16 * wv + quad * 4 + reg] = ya[reg];
    }
    __syncthreads();
    if (wv == 1) {
      const int rp = 127 & 3;
      unsigned bl = __float_as_uint(recs[rp][256 + (lane >> 5)]);
      unsigned bh = __float_as_uint(recs[rp][258 + (lane >> 5)]);
      float q0 = (float)((bl >> (lane & 31)) & 1u);
      float q1 = (float)((bh >> (lane & 31)) & 1u);
      float v = sigm(ypbuf[lane] + bab0) * q0 - recs[rp][128 + lane]
              + sigm(ypbuf[64 + lane] + bab0) * q1 - recs[rp][128 + 64 + lane];
      v += __shfl_xor(v, 32); v += __shfl_xor(v, 16); v += __shfl_xor(v, 8);
      v += __shfl_xor(v, 4);  v += __shfl_xor(v, 2);  v += __shfl_xor(v, 1);
      if (lane == 0) out[bS + 127] = sigm(recs[rp][260] * v);
    }
  }
}

// ---------------------------------------------------------------------------
extern "C" void kernel_launch(void* const* d_in, const int* in_sizes, int n_in,
                              void* d_out, int out_size, void* d_ws, size_t ws_size,
                              hipStream_t stream) {
  const int*   qs    = (const int*)d_in[0];
  const int*   cs    = (const int*)d_in[1];
  const float* qmat  = (const float*)d_in[2];
  const float* Eq    = (const float*)d_in[3];
  const float* Ec    = (const float*)d_in[4];
  const float* h0    = (const float*)d_in[5];
  const float* W1    = (const float*)d_in[6];
  const float* b1    = (const float*)d_in[7];
  const float* W2    = (const float*)d_in[8];
  const float* b2    = (const float*)d_in[9];
  const float* W3    = (const float*)d_in[10];
  const float* b3    = (const float*)d_in[11];
  const float* W4    = (const float*)d_in[12];
  const float* b4    = (const float*)d_in[13];
  const float* Wab   = (const float*)d_in[14];
  const float* bab   = (const float*)d_in[15];
  const float* Wdiff = (const float*)d_in[16];
  const float* bdiff = (const float*)d_in[17];
  const float* Wdisc = (const float*)d_in[18];
  const float* bdisc = (const float*)d_in[19];
  float* out = (float*)d_out;

  float* w = (float*)d_ws;
  float* Kws   = w;                       // 16384
  float* Uws   = Kws + 16384;             // 512
  float* T     = Uws + 512;               // 2000*256 = 512000
  float* DIFF  = T + 512000;              // 2000*128 = 256000
  float* DISCq = DIFF + 256000;           // 2000
  float* REC   = DISCq + 2000;            // 64*128*264 = 2,162,688

  pcK<<<5, 256, 0, stream>>>(W1, W2, W3, Ec, b1, Kws, Uws);
  pcT<<<2000, 128, 0, stream>>>(Eq, qmat, Wdiff, bdiff, Wdisc, bdisc, Kws, T, DIFF, DISCq);
  pcR<<<BB * SS, 128, 0, stream>>>(qs, cs, qmat, b2, b3, T, Uws, DIFF, DISCq, REC);
  lpkt_main<<<BB, 512, 0, stream>>>(h0, W2, W3, W4, b4, Wab, bab, REC, out);
}

// Round 5
// 533.531 us; speedup vs baseline: 1.1416x; 1.0590x over previous
//
#include <hip/hip_runtime.h>

// LPKT forward. B=64, S=128, NQ=2000, C=128, K=64, DE=DC=64.
// R5: asm barriers (lgkmcnt-only, no vmcnt drain), register-resident record
// stream, permuted-k LDS h layout (b64 writes / b128 reads, k_eff-matched
// MFMA B-fragments), reduced DS-instruction budget.

constexpr int BB = 64, SS = 128, CD = 128, KK = 64;
constexpr int RECF = 264;   // BASE2p[64]|BASE3p[64]|DIFF[128]|QBITS[4]|DISC|pad
constexpr int HP2  = 72;    // shorts per hsb row (144B, 16B-aligned)

typedef short bf16x8 __attribute__((ext_vector_type(8)));
typedef float f32x4  __attribute__((ext_vector_type(4)));

// barrier WITHOUT vmcnt drain: LDS ordering only
#define BAR() asm volatile("s_waitcnt lgkmcnt(0)\ns_barrier" ::: "memory")

__device__ __forceinline__ short f2bf(float x) {
  unsigned u = __builtin_bit_cast(unsigned, x);
  unsigned r = u + 0x7fffu + ((u >> 16) & 1u);
  return (short)(r >> 16);
}
__device__ __forceinline__ float bf2f(short s) {
  unsigned u = ((unsigned)(unsigned short)s) << 16;
  return __builtin_bit_cast(float, u);
}
__device__ __forceinline__ float sigm(float x) { return 1.f / (1.f + __expf(-x)); }
__device__ __forceinline__ bf16x8 pack8(float4 a, float4 b) {
  bf16x8 r;
  r[0] = f2bf(a.x); r[1] = f2bf(a.y); r[2] = f2bf(a.z); r[3] = f2bf(a.w);
  r[4] = f2bf(b.x); r[5] = f2bf(b.y); r[6] = f2bf(b.z); r[7] = f2bf(b.w);
  return r;
}
__device__ __forceinline__ void store_bf4(short* p, float a, float b, float c, float d) {
  union { short s[4]; uint2 u; } v;
  v.s[0] = f2bf(a); v.s[1] = f2bf(b); v.s[2] = f2bf(c); v.s[3] = f2bf(d);
  *(uint2*)p = v.u;
}

// ---------------------------------------------------------------------------
__global__ void pcK(const float* __restrict__ W1, const float* __restrict__ W2,
                    const float* __restrict__ W3, const float* __restrict__ Ec,
                    const float* __restrict__ b1,
                    float* __restrict__ Kws, float* __restrict__ Uws) {
  int m = blockIdx.x, tid = threadIdx.x;
  if (m < 4) {
    const float* src = (m < 2 ? W2 : W3) + (m & 1) * 64 * 64;
    int k = tid & 63, dg = tid >> 6;
    float acc[16];
    #pragma unroll
    for (int i = 0; i < 16; ++i) acc[i] = 0.f;
    for (int j = 0; j < 64; ++j) {
      float w = src[j * 64 + k];
      #pragma unroll
      for (int i = 0; i < 16; ++i) acc[i] += W1[(dg * 16 + i) * 64 + j] * w;
    }
    #pragma unroll
    for (int i = 0; i < 16; ++i) Kws[m * 4096 + (dg * 16 + i) * 64 + k] = acc[i];
  } else {
    __shared__ float alc[2][64];
    if (tid < 128) {
      int cr = tid >> 6, k = tid & 63;
      float s = b1[k];
      for (int d = 0; d < 64; ++d) s += Ec[cr * 64 + d] * W1[(64 + d) * 64 + k];
      alc[cr][k] = s;
    }
    __syncthreads();
    if (tid < 128) {
      int cr = tid >> 6, k = tid & 63;
      float u2a = 0.f, u2b = 0.f, u3a = 0.f, u3b = 0.f;
      for (int j = 0; j < 64; ++j) {
        float a = alc[cr][j];
        u2a += a * W2[j * 64 + k];       u2b += a * W2[(64 + j) * 64 + k];
        u3a += a * W3[j * 64 + k];       u3b += a * W3[(64 + j) * 64 + k];
      }
      Uws[(0 + cr) * 64 + k] = u2a;  Uws[(2 + cr) * 64 + k] = u2b;
      Uws[(4 + cr) * 64 + k] = u3a;  Uws[(6 + cr) * 64 + k] = u3b;
    }
  }
}

// ---------------------------------------------------------------------------
// pcT: 8 questions per block (250 blocks) -> 8x less redundant weight traffic.
__global__ void pcT(const float* __restrict__ Eq, const float* __restrict__ qmat,
                    const float* __restrict__ Wdiff, const float* __restrict__ bdiff,
                    const float* __restrict__ Wdisc, const float* __restrict__ bdisc,
                    const float* __restrict__ Kws,
                    float* __restrict__ T, float* __restrict__ DIFF, float* __restrict__ DISCq) {
  int q0 = blockIdx.x * 8, tid = threadIdx.x;
  __shared__ float e[8][64];
  for (int i = tid; i < 512; i += 256) e[i >> 6][i & 63] = Eq[(q0 + (i >> 6)) * 64 + (i & 63)];
  __syncthreads();
  {
    int m = tid >> 6, k = tid & 63;
    float acc[8] = {0.f, 0.f, 0.f, 0.f, 0.f, 0.f, 0.f, 0.f};
    for (int d = 0; d < 64; ++d) {
      float w = Kws[m * 4096 + d * 64 + k];
      #pragma unroll
      for (int qq = 0; qq < 8; ++qq) acc[qq] += e[qq][d] * w;
    }
    #pragma unroll
    for (int qq = 0; qq < 8; ++qq) T[(q0 + qq) * 256 + m * 64 + k] = acc[qq];
  }
  if (tid < 128) {
    int c = tid;
    float acc[8] = {0.f, 0.f, 0.f, 0.f, 0.f, 0.f, 0.f, 0.f};
    for (int d = 0; d < 64; ++d) {
      float w = Wdiff[d * 128 + c];
      #pragma unroll
      for (int qq = 0; qq < 8; ++qq) acc[qq] += e[qq][d] * w;
    }
    #pragma unroll
    for (int qq = 0; qq < 8; ++qq)
      DIFF[(q0 + qq) * 128 + c] = qmat[(q0 + qq) * 128 + c] * sigm(acc[qq] + bdiff[c]);
  } else if (tid < 136) {
    int qq = tid - 128;
    float s = 0.f;
    for (int d = 0; d < 64; ++d) s += e[qq][d] * Wdisc[d];
    DISCq[q0 + qq] = 5.f * sigm(s + bdisc[0]);
  }
}

// ---------------------------------------------------------------------------
// pcR: per-(b,t) record. BASE2/BASE3 written k-PERMUTED: pos=(k&15)*4+(k>>4).
__global__ void pcR(const int* __restrict__ qs, const int* __restrict__ cs,
                    const float* __restrict__ qmat,
                    const float* __restrict__ b2, const float* __restrict__ b3,
                    const float* __restrict__ T, const float* __restrict__ Uws,
                    const float* __restrict__ DIFF, const float* __restrict__ DISCq,
                    float* __restrict__ REC) {
  int bs = blockIdx.x;
  int t  = bs & (SS - 1);
  int tid = threadIdx.x;
  int q_t = qs[bs];
  float* rec = REC + (size_t)bs * RECF;
  if (tid < 64) {
    int k = tid;
    float v2 = b2[k], v3 = b3[k];
    if (t >= 1) {
      int q1 = qs[bs - 1], c1 = cs[bs - 1];
      v2 += T[q1 * 256 + 64 + k]  + Uws[(2 + c1) * 64 + k];
      v3 += T[q1 * 256 + 192 + k] + Uws[(6 + c1) * 64 + k];
    }
    if (t >= 2) {
      int q2 = qs[bs - 2], c2 = cs[bs - 2];
      v2 += T[q2 * 256 + k]       + Uws[(0 + c2) * 64 + k];
      v3 += T[q2 * 256 + 128 + k] + Uws[(4 + c2) * 64 + k];
    }
    int pp = (k & 15) * 4 + (k >> 4);
    rec[pp] = v2; rec[64 + pp] = v3;
  }
  rec[128 + tid] = DIFF[q_t * 128 + tid];
  unsigned long long m = __ballot(qmat[q_t * 128 + tid] > 0.5f);
  int wv = tid >> 6, lane = tid & 63;
  if (lane == 0) {
    rec[256 + wv * 2]     = __uint_as_float((unsigned)m);
    rec[256 + wv * 2 + 1] = __uint_as_float((unsigned)(m >> 32));
  }
  if (tid == 0) rec[260] = DISCq[q_t];
}

// ---------------------------------------------------------------------------
// Main. grid=64, block=512 (8 waves). Wave w owns c-band [16w,16w+16).
// hsb permuted-k bf16; all MFMA B-fragments built with matching k_eff.
__global__ __launch_bounds__(512, 1) void lpkt_main(
    const float* __restrict__ h0,
    const float* __restrict__ W2, const float* __restrict__ W3,
    const float* __restrict__ W4, const float* __restrict__ b4,
    const float* __restrict__ Wab, const float* __restrict__ bab,
    const float* __restrict__ REC, float* __restrict__ out) {
  __shared__ __align__(16) short hsb[CD * HP2];             // 18432 B
  __shared__ __align__(16) short w23f[2 * 4 * 2 * 64 * 8];  //  8192 B
  __shared__ __align__(16) short lgb[64];                   // permuted lg (bf16)
  __shared__ __align__(16) float htbuf[2][64];              // permuted h_tilde acc
  __shared__ __align__(16) float ypbuf[128];                // raw ability dots

  const int b    = blockIdx.x;
  const int tid  = threadIdx.x;
  const int lane = tid & 63;
  const int wv   = tid >> 6;
  const int col  = lane & 15;
  const int quad = lane >> 4;
  const int bS   = b * SS;
  const int c0   = 16 * wv + 4 * quad;
  const float bab0 = bab[0];
  const f32x4 zz = {0.f, 0.f, 0.f, 0.f};

  const float* W4a = W4;
  const float* W4b = W4 + 64 * 64;
  const float* W2c = W2 + 128 * 64;
  const float* W3c = W3 + 128 * 64;

  // ---- persistent B-fragments with k_eff permutation ----
  bf16x8 bw4[4][2], bwb[4][2], bwab[2];
  float b4r[4], b2r[4], b3r[4];
  #pragma unroll
  for (int nb = 0; nb < 4; ++nb) {
    #pragma unroll
    for (int half = 0; half < 2; ++half)
      #pragma unroll
      for (int j = 0; j < 8; ++j) {
        int p  = half * 32 + quad * 8 + j;
        int ke = (p & 3) * 16 + (p >> 2);
        bw4[nb][half][j] = f2bf(W4a[ke * 64 + nb * 16 + col]);
        bwb[nb][half][j] = f2bf(W4b[ke * 64 + nb * 16 + col]);
      }
    b4r[nb] = b4[nb * 16 + col];
    b2r[nb] = 0.f; b3r[nb] = 0.f;  // bases come fully from REC
  }
  #pragma unroll
  for (int half = 0; half < 2; ++half)
    #pragma unroll
    for (int j = 0; j < 8; ++j) {
      int p  = half * 32 + quad * 8 + j;
      int ke = (p & 3) * 16 + (p >> 2);
      bwab[half][j] = (col == 0) ? f2bf(Wab[ke]) : (short)0;
    }

  // ---- W2c/W3c fragments into LDS (wave0's per-step LG) ----
  for (int e2 = tid; e2 < 1024; e2 += 512) {
    int lane_ = e2 & 63, half = (e2 >> 6) & 1, nb = (e2 >> 7) & 3, m = e2 >> 9;
    int q_ = lane_ >> 4, c_ = lane_ & 15;
    const float* src = m ? W3c : W2c;
    bf16x8 f;
    #pragma unroll
    for (int j = 0; j < 8; ++j) {
      int p  = half * 32 + q_ * 8 + j;
      int ke = (p & 3) * 16 + (p >> 2);
      f[j] = f2bf(src[ke * 64 + nb * 16 + c_]);
    }
    *(bf16x8*)&w23f[(((m * 4 + nb) * 2 + half) * 64 + lane_) * 8] = f;
  }

  // ---- h init: fp32 regs + permuted bf16 LDS ----
  float h2[4][4];
  #pragma unroll
  for (int reg = 0; reg < 4; ++reg) {
    int c = c0 + reg;
    #pragma unroll
    for (int n = 0; n < 4; ++n) h2[reg][n] = h0[c * 64 + n * 16 + col];
    store_bf4(&hsb[c * HP2 + col * 4], h2[reg][0], h2[reg][1], h2[reg][2], h2[reg][3]);
  }
  if (tid < 128) htbuf[tid >> 6][tid & 63] = 0.f;
  if (tid == 0) out[bS] = 0.f;
  __syncthreads();

  // ---- initial h_tilde (bits(0) . h0) into htbuf[1] ----
  float qeR[4];
  {
    unsigned qw = __float_as_uint(REC[(size_t)bS * RECF + 256 + (wv >> 1)]);
    #pragma unroll
    for (int reg = 0; reg < 4; ++reg) qeR[reg] = (float)((qw >> ((c0 & 31) + reg)) & 1u);
    float pk[4];
    #pragma unroll
    for (int n = 0; n < 4; ++n) {
      pk[n] = qeR[0] * h2[0][n] + qeR[1] * h2[1][n] + qeR[2] * h2[2][n] + qeR[3] * h2[3][n];
      pk[n] += __shfl_xor(pk[n], 16);
      pk[n] += __shfl_xor(pk[n], 32);
    }
    if (quad == 0) {
      #pragma unroll
      for (int n = 0; n < 4; ++n) atomicAdd(&htbuf[1][col * 4 + n], pk[n]);
    }
  }

  // ---- register prefetch pipelines (2 steps ahead) ----
  unsigned qbw[2];
  qbw[1] = __float_as_uint(REC[(size_t)(bS + 1) * RECF + 256 + (wv >> 1)]);
  qbw[0] = __float_as_uint(REC[(size_t)(bS + 2) * RECF + 256 + (wv >> 1)]);
  float4 pb2[2], pb3[2];
  if (wv == 0) {
    pb2[1] = *(const float4*)&REC[(size_t)(bS + 1) * RECF + col * 4];
    pb3[1] = *(const float4*)&REC[(size_t)(bS + 1) * RECF + 64 + col * 4];
    pb2[0] = *(const float4*)&REC[(size_t)(bS + 2) * RECF + col * 4];
    pb3[0] = *(const float4*)&REC[(size_t)(bS + 2) * RECF + 64 + col * 4];
  }
  float yd0[3], yd1[3], ydc[3];
  unsigned yq0[3], yq1[3];
  if (wv == 1) {
    const float* rp = REC + (size_t)(bS + 1) * RECF;
    yd0[1] = rp[128 + lane]; yd1[1] = rp[192 + lane]; ydc[1] = rp[260];
    yq0[1] = __float_as_uint(rp[256 + (lane >> 5)]);
    yq1[1] = __float_as_uint(rp[258 + (lane >> 5)]);
  }
  __syncthreads();

  float qnR[4];

  for (int t = 1; t < SS; ++t) {
    // ================= P =================
    // qn(t) bits, then reissue slot for t+2
    {
      unsigned qw = qbw[t & 1];
      #pragma unroll
      for (int reg = 0; reg < 4; ++reg) qnR[reg] = (float)((qw >> ((c0 & 31) + reg)) & 1u);
      int tn = (t + 2 < SS) ? t + 2 : SS - 1;
      qbw[t & 1] = __float_as_uint(REC[(size_t)(bS + tn) * RECF + 256 + (wv >> 1)]);
    }
    // A-frags of h(t-1)
    bf16x8 af0 = *(const bf16x8*)&hsb[(16 * wv + col) * HP2 + quad * 8];
    bf16x8 af1 = *(const bf16x8*)&hsb[(16 * wv + col) * HP2 + 32 + quad * 8];
    // G = h @ W4a ; ability dot of h(t-1)
    f32x4 acc[4];
    #pragma unroll
    for (int nb = 0; nb < 4; ++nb) {
      acc[nb] = __builtin_amdgcn_mfma_f32_16x16x32_bf16(af0, bw4[nb][0], zz, 0, 0, 0);
      acc[nb] = __builtin_amdgcn_mfma_f32_16x16x32_bf16(af1, bw4[nb][1], acc[nb], 0, 0, 0);
    }
    f32x4 ya = __builtin_amdgcn_mfma_f32_16x16x32_bf16(af0, bwab[0], zz, 0, 0, 0);
    ya = __builtin_amdgcn_mfma_f32_16x16x32_bf16(af1, bwab[1], ya, 0, 0, 0);
    if (col == 0) *(float4*)&ypbuf[c0] = make_float4(ya[0], ya[1], ya[2], ya[3]);
    // zero next-parity h_tilde accumulator
    if (wv == 3) htbuf[(t + 1) & 1][lane] = 0.f;
    // wave0: LG
    if (wv == 0) {
      float4 base2 = pb2[t & 1], base3 = pb3[t & 1];
      {
        int tn = (t + 2 < SS) ? t + 2 : SS - 1;
        pb2[t & 1] = *(const float4*)&REC[(size_t)(bS + tn) * RECF + col * 4];
        pb3[t & 1] = *(const float4*)&REC[(size_t)(bS + tn) * RECF + 64 + col * 4];
      }
      const float* htb = htbuf[t & 1];
      float4 x0 = *(const float4*)&htb[quad * 8];
      float4 x1 = *(const float4*)&htb[quad * 8 + 4];
      float4 x2 = *(const float4*)&htb[32 + quad * 8];
      float4 x3 = *(const float4*)&htb[32 + quad * 8 + 4];
      bf16x8 hf0 = pack8(x0, x1), hf1 = pack8(x2, x3);
      float lgn[4];
      #pragma unroll
      for (int nb = 0; nb < 4; ++nb) {
        bf16x8 w20 = *(const bf16x8*)&w23f[(((0 * 4 + nb) * 2 + 0) * 64 + lane) * 8];
        bf16x8 w21 = *(const bf16x8*)&w23f[(((0 * 4 + nb) * 2 + 1) * 64 + lane) * 8];
        bf16x8 w30 = *(const bf16x8*)&w23f[(((1 * 4 + nb) * 2 + 0) * 64 + lane) * 8];
        bf16x8 w31 = *(const bf16x8*)&w23f[(((1 * 4 + nb) * 2 + 1) * 64 + lane) * 8];
        f32x4 a2 = __builtin_amdgcn_mfma_f32_16x16x32_bf16(hf0, w20, zz, 0, 0, 0);
        a2 = __builtin_amdgcn_mfma_f32_16x16x32_bf16(hf1, w21, a2, 0, 0, 0);
        f32x4 a3 = __builtin_amdgcn_mfma_f32_16x16x32_bf16(hf0, w30, zz, 0, 0, 0);
        a3 = __builtin_amdgcn_mfma_f32_16x16x32_bf16(hf1, w31, a3, 0, 0, 0);
        float u2 = a2[0] + ((const float*)&base2)[nb];
        float u3 = a3[0] + ((const float*)&base3)[nb];
        lgn[nb] = sigm(u3) * sigm(2.f * u2);
      }
      if (quad == 0) store_bf4(&lgb[col * 4], lgn[0], lgn[1], lgn[2], lgn[3]);
    } else if (wv == 1) {   // y-field prefetch for tau = t+1
      int tn = (t + 1 < SS) ? t + 1 : SS - 1;
      int sl = (t + 1) % 3;
      const float* rp = REC + (size_t)(bS + tn) * RECF;
      yd0[sl] = rp[128 + lane]; yd1[sl] = rp[192 + lane]; ydc[sl] = rp[260];
      yq0[sl] = __float_as_uint(rp[256 + (lane >> 5)]);
      yq1[sl] = __float_as_uint(rp[258 + (lane >> 5)]);
    }
    BAR();   // B1: lg published; ypbuf published

    // ================= Q =================
    float lgv[4];
    {
      uint2 lraw = *(const uint2*)&lgb[col * 4];
      lgv[0] = bf2f((short)(lraw.x & 0xffff)); lgv[1] = bf2f((short)(lraw.x >> 16));
      lgv[2] = bf2f((short)(lraw.y & 0xffff)); lgv[3] = bf2f((short)(lraw.y >> 16));
    }
    bf16x8 lf0 = *(const bf16x8*)&lgb[quad * 8];
    bf16x8 lf1 = *(const bf16x8*)&lgb[32 + quad * 8];
    float tvv[4];
    #pragma unroll
    for (int nb = 0; nb < 4; ++nb) {
      f32x4 bb = __builtin_amdgcn_mfma_f32_16x16x32_bf16(lf0, bwb[nb][0], zz, 0, 0, 0);
      bb = __builtin_amdgcn_mfma_f32_16x16x32_bf16(lf1, bwb[nb][1], bb, 0, 0, 0);
      tvv[nb] = bb[0] + b4r[nb];
    }
    // gates + h update + permuted bf16 writeback
    #pragma unroll
    for (int reg = 0; reg < 4; ++reg) {
      int c = c0 + reg;
      #pragma unroll
      for (int n = 0; n < 4; ++n) {
        float g = sigm(acc[n][reg] + tvv[n]);
        h2[reg][n] = qeR[reg] * lgv[n] + g * h2[reg][n];
      }
      store_bf4(&hsb[c * HP2 + col * 4], h2[reg][0], h2[reg][1], h2[reg][2], h2[reg][3]);
    }
    // h_tilde(t) partials -> htbuf[(t+1)&1]
    {
      float pk[4];
      #pragma unroll
      for (int n = 0; n < 4; ++n) {
        pk[n] = qnR[0] * h2[0][n] + qnR[1] * h2[1][n] + qnR[2] * h2[2][n] + qnR[3] * h2[3][n];
        pk[n] += __shfl_xor(pk[n], 16);
        pk[n] += __shfl_xor(pk[n], 32);
      }
      if (quad == 0) {
        #pragma unroll
        for (int n = 0; n < 4; ++n) atomicAdd(&htbuf[(t + 1) & 1][col * 4 + n], pk[n]);
      }
    }
    // wave1: finish y(t-1)
    if (wv == 1 && t >= 2) {
      int sl = (t - 1) % 3;
      float qa = (float)((yq0[sl] >> (lane & 31)) & 1u);
      float qb = (float)((yq1[sl] >> (lane & 31)) & 1u);
      float v = sigm(ypbuf[lane] + bab0) * qa - yd0[sl]
              + sigm(ypbuf[64 + lane] + bab0) * qb - yd1[sl];
      v += __shfl_xor(v, 32); v += __shfl_xor(v, 16); v += __shfl_xor(v, 8);
      v += __shfl_xor(v, 4);  v += __shfl_xor(v, 2);  v += __shfl_xor(v, 1);
      if (lane == 0) out[bS + t - 1] = sigm(ydc[sl] * v);
    }
    #pragma unroll
    for (int reg = 0; reg < 4; ++reg) qeR[reg] = qnR[reg];
    BAR();   // B2: hsb/htbuf published
  }

  // ---- epilogue: y(127) ----
  {
    bf16x8 af0 = *(const bf16x8*)&hsb[(16 * wv + col) * HP2 + quad * 8];
    bf16x8 af1 = *(const bf16x8*)&hsb[(16 * wv + col) * HP2 + 32 + quad * 8];
    f32x4 ya = __builtin_amdgcn_mfma_f32_16x16x32_bf16(af0, bwab[0], zz, 0, 0, 0);
    ya = __builtin_amdgcn_mfma_f32_16x16x32_bf16(af1, bwab[1], ya, 0, 0, 0);
    if (col == 0) *(float4*)&ypbuf[c0] = make_float4(ya[0], ya[1], ya[2], ya[3]);
    BAR();
    if (wv == 1) {
      int sl = 127 % 3;   // issued at t=126
      float qa = (float)((yq0[sl] >> (lane & 31)) & 1u);
      float qb = (float)((yq1[sl] >> (lane & 31)) & 1u);
      float v = sigm(ypbuf[lane] + bab0) * qa - yd0[sl]
              + sigm(ypbuf[64 + lane] + bab0) * qb - yd1[sl];
      v += __shfl_xor(v, 32); v += __shfl_xor(v, 16); v += __shfl_xor(v, 8);
      v += __shfl_xor(v, 4);  v += __shfl_xor(v, 2);  v += __shfl_xor(v, 1);
      if (lane == 0) out[bS + 127] = sigm(ydc[sl] * v);
    }
  }
}

// ---------------------------------------------------------------------------
extern "C" void kernel_launch(void* const* d_in, const int* in_sizes, int n_in,
                              void* d_out, int out_size, void* d_ws, size_t ws_size,
                              hipStream_t stream) {
  const int*   qs    = (const int*)d_in[0];
  const int*   cs    = (const int*)d_in[1];
  const float* qmat  = (const float*)d_in[2];
  const float* Eq    = (const float*)d_in[3];
  const float* Ec    = (const float*)d_in[4];
  const float* h0    = (const float*)d_in[5];
  const float* W1    = (const float*)d_in[6];
  const float* b1    = (const float*)d_in[7];
  const float* W2    = (const float*)d_in[8];
  const float* b2    = (const float*)d_in[9];
  const float* W3    = (const float*)d_in[10];
  const float* b3    = (const float*)d_in[11];
  const float* W4    = (const float*)d_in[12];
  const float* b4    = (const float*)d_in[13];
  const float* Wab   = (const float*)d_in[14];
  const float* bab   = (const float*)d_in[15];
  const float* Wdiff = (const float*)d_in[16];
  const float* bdiff = (const float*)d_in[17];
  const float* Wdisc = (const float*)d_in[18];
  const float* bdisc = (const float*)d_in[19];
  float* out = (float*)d_out;

  float* w = (float*)d_ws;
  float* Kws   = w;                       // 16384
  float* Uws   = Kws + 16384;             // 512
  float* T     = Uws + 512;               // 512000
  float* DIFF  = T + 512000;              // 256000
  float* DISCq = DIFF + 256000;           // 2000
  float* REC   = DISCq + 2000;            // 8192*264

  pcK<<<5, 256, 0, stream>>>(W1, W2, W3, Ec, b1, Kws, Uws);
  pcT<<<250, 256, 0, stream>>>(Eq, qmat, Wdiff, bdiff, Wdisc, bdisc, Kws, T, DIFF, DISCq);
  pcR<<<BB * SS, 128, 0, stream>>>(qs, cs, qmat, b2, b3, T, Uws, DIFF, DISCq, REC);
  lpkt_main<<<BB, 512, 0, stream>>>(h0, W2, W3, W4, b4, Wab, bab, REC, out);
}